// Round 3
// baseline (665.562 us; speedup 1.0000x reference)
//
#include <hip/hip_runtime.h>
#include <cmath>

#define NBLK 3456   // 2 * 12 * 12 * 12 blocks of 16^3

#define DPP_SHR1 0x111   // y-1 neighbor source (row_shr:1)
#define DPP_SHL1 0x101   // y+1 neighbor source (row_shl:1)

// old = v, bound_ctrl = 0: row-edge lanes keep v  -> op(v,v)=v = pad identity
// for min/max/and/or.  Fusable to single v_op_dpp.
template<int CTRL>
__device__ __forceinline__ float dpp_keep_f(float v) {
  return __int_as_float(__builtin_amdgcn_update_dpp(
      __float_as_int(v), __float_as_int(v), CTRL, 0xF, 0xF, false));
}
// bound_ctrl = 1: row-edge lanes get 0 -> exact 0-pad for sums/AND-with-0-pad.
template<int CTRL>
__device__ __forceinline__ float dpp_zero_f(float v) {
  return __int_as_float(__builtin_amdgcn_update_dpp(
      0, __float_as_int(v), CTRL, 0xF, 0xF, true));
}
template<int CTRL>
__device__ __forceinline__ unsigned dpp_keep_u(unsigned v) {
  return (unsigned)__builtin_amdgcn_update_dpp((int)v, (int)v, CTRL, 0xF, 0xF, false);
}
template<int CTRL>
__device__ __forceinline__ unsigned dpp_zero_u(unsigned v) {
  return (unsigned)__builtin_amdgcn_update_dpp(0, (int)v, CTRL, 0xF, 0xF, true);
}

// LDS column layout: float4 chunk c (z=4c..4c+3) of column (x,y) at
// index (c*18 + x+1)*16 + y.  x pad slots at x=-1 -> 0 and x=16 -> 17.
#define COL_IDX(c, xx) (((c)*18 + (xx) + 1)*16 + y)

__global__ __launch_bounds__(256, 8)
void fused_blocks(const float* __restrict__ pred, const float* __restrict__ gtp,
                  const float* __restrict__ w1p, const float* __restrict__ w2p,
                  float* __restrict__ acc,   // 5 f32 sums + u32 ticket (zeroed)
                  float* __restrict__ out)
{
  __shared__ float4 buf[1152];                    // 18432 B, multi-purpose
  unsigned* m_ex = (unsigned*)buf;                // 288 u32 (bytes 0..1151)
  float*    red  = ((float*)buf) + 512;           // 36 f32  (bytes 2048..2191)

  const int tid = threadIdx.x;
  const int x = tid >> 4;
  const int y = tid & 15;

  const int b  = blockIdx.x;
  const int n  = b / 1728;
  const int r  = b - n * 1728;
  const int bz = r / 144;
  const int r2 = r - bz * 144;
  const int bx = r2 / 12;
  const int by = r2 - bx * 12;

  const size_t base = (size_t)(n * 192 + bz * 16) * 36864
                    + (size_t)(bx * 16 + x) * 192 + (size_t)(by * 16 + y);

  const float INF = __builtin_inff();

  auto write_pads = [&](float pv) {
    if (tid < 128) {
      const int c  = tid >> 5;
      const int xi = ((tid >> 4) & 1) ? 17 : 0;
      const int yy = tid & 15;
      buf[(c * 18 + xi) * 16 + yy] = make_float4(pv, pv, pv, pv);
    }
  };

  // ---- loads: p column + g column (g consumed immediately) ----
  float p[16];
  #pragma unroll
  for (int z = 0; z < 16; ++z) p[z] = pred[base + (size_t)z * 36864];

  unsigned gm = 0u;
  float sp2 = 0.f, spg = 0.f;
  #pragma unroll
  for (int z = 0; z < 16; ++z) {
    float gz = gtp[base + (size_t)z * 36864];
    sp2 = fmaf(p[z], p[z], sp2);
    spg = fmaf(p[z], gz, spg);
    if (gz > 0.5f) gm |= (1u << z);
  }

  // ---------------- pred boundary (3^3 laplacian, zero pad) ----------------
  float szy[16];
  {
    float sy[16];
    #pragma unroll
    for (int z = 0; z < 16; ++z) {
      float v = p[z];
      sy[z] = v + dpp_zero_f<DPP_SHR1>(v) + dpp_zero_f<DPP_SHL1>(v);
    }
    #pragma unroll
    for (int z = 0; z < 16; ++z) {
      float s = sy[z];
      if (z > 0)  s += sy[z-1];
      if (z < 15) s += sy[z+1];
      szy[z] = s;
    }
  }
  #pragma unroll
  for (int c = 0; c < 4; ++c)
    buf[COL_IDX(c, x)] = make_float4(szy[4*c], szy[4*c+1], szy[4*c+2], szy[4*c+3]);
  write_pads(0.f);
  __syncthreads();                                             // L1

  unsigned pm_bdr = 0u;
  #pragma unroll
  for (int c = 0; c < 4; ++c) {
    float4 a4 = buf[COL_IDX(c, x - 1)];
    float4 b4 = buf[COL_IDX(c, x + 1)];
    float sm[4] = {a4.x + b4.x, a4.y + b4.y, a4.z + b4.z, a4.w + b4.w};
    #pragma unroll
    for (int j = 0; j < 4; ++j) {
      const int z = 4*c + j;
      float bb = fmaf(27.f, p[z], -(szy[z] + sm[j]));
      if (bb > 0.1f) pm_bdr |= (1u << z);
    }
  }
  __syncthreads();                                             // L2

  // ---------------- pred soft skeleton (4x erode+dilate) ----------------
  #pragma unroll
  for (int c = 0; c < 4; ++c)
    buf[COL_IDX(c, x)] = make_float4(p[4*c], p[4*c+1], p[4*c+2], p[4*c+3]);
  write_pads(INF);
  __syncthreads();                                             // B0

  float cur[16], skl[16];
  #pragma unroll
  for (int z = 0; z < 16; ++z) { cur[z] = p[z]; skl[z] = 0.f; }

  for (int k = 0; k < 4; ++k) {
    float xm[16], xp[16];
    #pragma unroll
    for (int c = 0; c < 4; ++c) {
      float4 a4 = buf[COL_IDX(c, x - 1)];
      float4 b4 = buf[COL_IDX(c, x + 1)];
      xm[4*c] = a4.x; xm[4*c+1] = a4.y; xm[4*c+2] = a4.z; xm[4*c+3] = a4.w;
      xp[4*c] = b4.x; xp[4*c+1] = b4.y; xp[4*c+2] = b4.z; xp[4*c+3] = b4.w;
    }
    // erode: min over 7-point cross (+INF pads are in LDS / DPP identity)
    float en[16];
    #pragma unroll
    for (int z = 0; z < 16; ++z) {
      float v = cur[z];
      float m = fminf(v, fminf(dpp_keep_f<DPP_SHR1>(v), dpp_keep_f<DPP_SHL1>(v)));
      if (z > 0)  m = fminf(m, cur[z-1]);
      if (z < 15) m = fminf(m, cur[z+1]);
      en[z] = fminf(m, fminf(xm[z], xp[z]));
    }
    // dilate(en) in y,z (in-register)
    float ty[16], tz[16];
    #pragma unroll
    for (int z = 0; z < 16; ++z) {
      float v = en[z];
      ty[z] = fmaxf(v, fmaxf(dpp_keep_f<DPP_SHR1>(v), dpp_keep_f<DPP_SHL1>(v)));
    }
    #pragma unroll
    for (int z = 0; z < 16; ++z) {
      float m = ty[z];
      if (z > 0)  m = fmaxf(m, ty[z-1]);
      if (z < 15) m = fmaxf(m, ty[z+1]);
      tz[z] = m;
    }
    __syncthreads();                                           // B1: cur reads done
    #pragma unroll
    for (int c = 0; c < 4; ++c)
      buf[COL_IDX(c, x)] = make_float4(tz[4*c], tz[4*c+1], tz[4*c+2], tz[4*c+3]);
    write_pads(-INF);
    __syncthreads();                                           // B2: tz visible
    #pragma unroll
    for (int c = 0; c < 4; ++c) {
      float4 a4 = buf[COL_IDX(c, x - 1)];
      float4 b4 = buf[COL_IDX(c, x + 1)];
      float dm[4] = {fmaxf(a4.x, b4.x), fmaxf(a4.y, b4.y),
                     fmaxf(a4.z, b4.z), fmaxf(a4.w, b4.w)};
      #pragma unroll
      for (int j = 0; j < 4; ++j) {
        const int z = 4*c + j;
        float D = fmaxf(tz[z], dm[j]);
        float delta = fmaxf(cur[z] - D, 0.f);
        skl[z] += fmaxf(fmaf(-skl[z], delta, delta), 0.f);
        cur[z] = en[z];
      }
    }
    if (k < 3) {
      __syncthreads();                                         // B3: tz reads done
      #pragma unroll
      for (int c = 0; c < 4; ++c)
        buf[COL_IDX(c, x)] = make_float4(en[4*c], en[4*c+1], en[4*c+2], en[4*c+3]);
      write_pads(INF);
      __syncthreads();                                         // B4: en visible
    }
  }
  __syncthreads();   // float-buf reads done before m_ex overlay

  // ---------------- gt phase: exact bit-domain morphology ----------------
  // gt boundary: bdr = g & ~AND27(g) with zero padding
  unsigned ly  = gm & dpp_zero_u<DPP_SHR1>(gm) & dpp_zero_u<DPP_SHL1>(gm);
  unsigned lzy = ly & (ly >> 1) & ((ly << 1) & 0xFFFFu);
  m_ex[(x + 1) * 16 + y] = lzy;
  if (tid < 32) m_ex[((tid >> 4) ? 17 : 0) * 16 + (tid & 15)] = 0u;
  __syncthreads();                                             // G1
  unsigned gm_bdr = gm & ~(m_ex[x * 16 + y] & lzy & m_ex[(x + 2) * 16 + y]);

  // gt soft skeleton in bits (erode=AND w/ 1-pad, dilate=OR w/ 0-pad)
  unsigned curm = gm, sklm = 0u;
  for (int k = 0; k < 4; ++k) {
    __syncthreads();                                           // G2
    m_ex[(x + 1) * 16 + y] = curm;
    if (tid < 32) m_ex[((tid >> 4) ? 17 : 0) * 16 + (tid & 15)] = 0xFFFFu;
    __syncthreads();                                           // G3
    unsigned em = curm
        & dpp_keep_u<DPP_SHR1>(curm) & dpp_keep_u<DPP_SHL1>(curm)
        & ((curm >> 1) | 0x8000u) & ((curm << 1) | 1u)
        & m_ex[x * 16 + y] & m_ex[(x + 2) * 16 + y];
    em &= 0xFFFFu;
    unsigned dy  = em | dpp_keep_u<DPP_SHR1>(em) | dpp_keep_u<DPP_SHL1>(em);
    unsigned dzy = (dy | (dy >> 1) | (dy << 1)) & 0xFFFFu;
    __syncthreads();                                           // G4
    m_ex[(x + 1) * 16 + y] = dzy;
    if (tid < 32) m_ex[((tid >> 4) ? 17 : 0) * 16 + (tid & 15)] = 0u;
    __syncthreads();                                           // G5
    unsigned D = m_ex[x * 16 + y] | dzy | m_ex[(x + 2) * 16 + y];
    sklm |= curm & ~D;
    curm = em;
  }

  // ---------------- per-block reductions ----------------
  float vals[9];
  {
    float tcl = 0.f, scl = 0.f;
    #pragma unroll
    for (int z = 0; z < 16; ++z) {
      scl += skl[z];
      tcl += ((sklm >> z) & 1u) ? skl[z] : 0.f;
    }
    vals[0] = tcl;                                   // sum g_cl * p_cl
    vals[1] = scl;                                   // sum p_cl
    vals[2] = (float)__popc(sklm);                   // sum g_cl
    vals[3] = (float)__popc(pm_bdr & gm_bdr);        // bdr tp
    vals[4] = (float)__popc(pm_bdr);                 // sum p_bdr
    vals[5] = (float)__popc(gm_bdr);                 // sum g_bdr
    vals[6] = spg;                                   // dice: sum p*g
    vals[7] = sp2;                                   // dice: sum p*p
    vals[8] = (float)__popc(gm);                     // dice: sum g*g
  }
  #pragma unroll
  for (int j = 0; j < 9; ++j) {
    float v = vals[j];
    #pragma unroll
    for (int off = 32; off; off >>= 1) v += __shfl_xor(v, off);
    vals[j] = v;
  }
  if ((tid & 63) == 0) {
    #pragma unroll
    for (int j = 0; j < 9; ++j) red[(tid >> 6) * 9 + j] = vals[j];
  }
  __syncthreads();                                             // R1
  if (tid == 0) {
    float t[9];
    #pragma unroll
    for (int j = 0; j < 9; ++j) t[j] = red[j] + red[9 + j] + red[18 + j] + red[27 + j];
    const float s = 1e-8f;
    // boundary tversky
    float tp = t[3], fp = t[4] - t[3], fn = t[5] - t[3];
    float den = fp + fn + s;
    float alpha = 0.5f + 0.5f * ((fp + s) / den);
    float beta  = 0.5f + 0.5f * ((fn + s) / den);
    float lb = 1.f - (tp + s) / (tp + alpha * fp + beta * fn + s);
    // centerline tversky
    float tpc = t[0], fpc = t[1] - t[0], fnc = t[2] - t[0];
    float denc = fpc + fnc + s;
    float alphac = 0.5f + 0.5f * ((fpc + s) / denc);
    float betac  = 0.5f + 0.5f * ((fnc + s) / denc);
    float lc = 1.f - (tpc + s) / (tpc + alphac * fpc + betac * fnc + s);

    atomicAdd(&acc[0], lb);
    atomicAdd(&acc[1], lc);
    atomicAdd(&acc[2], t[6]);
    atomicAdd(&acc[3], t[7]);
    atomicAdd(&acc[4], t[8]);
    __threadfence();
    unsigned* cnt = (unsigned*)(acc + 5);
    unsigned ticket = atomicAdd(cnt, 1u);
    if (ticket == NBLK - 1) {                 // last block: finalize
      double t0 = (double)atomicAdd(&acc[0], 0.f);
      double t1 = (double)atomicAdd(&acc[1], 0.f);
      double t2 = (double)atomicAdd(&acc[2], 0.f);
      double t3 = (double)atomicAdd(&acc[3], 0.f);
      double t4 = (double)atomicAdd(&acc[4], 0.f);
      double denom = t3 + t4;
      if (denom < 1e-6) denom = 1e-6;
      double dice = 2.0 * t2 / denom;
      double dl = 1.0 - dice;
      double w1 = (double)w1p[0], w2 = (double)w2p[0];
      double edge = (t0 / (w1 * w1) + t1 / (w2 * w2)) / (2.0 * (double)NBLK)
                  + log(1.0 + fabs(w1) * fabs(w2));
      out[0] = (float)((dice < 0.8) ? dl : (dl + edge));
    }
  }
}

extern "C" void kernel_launch(void* const* d_in, const int* in_sizes, int n_in,
                              void* d_out, int out_size, void* d_ws, size_t ws_size,
                              hipStream_t stream)
{
  const float* pred = (const float*)d_in[0];
  const float* gtp  = (const float*)d_in[1];
  const float* w1   = (const float*)d_in[2];
  const float* w2   = (const float*)d_in[3];

  hipMemsetAsync(d_ws, 0, 32, stream);   // 5 f32 accumulators + ticket counter
  fused_blocks<<<NBLK, 256, 0, stream>>>(pred, gtp, w1, w2,
                                         (float*)d_ws, (float*)d_out);
}

// Round 4
// 386.835 us; speedup vs baseline: 1.7205x; 1.7205x over previous
//
#include <hip/hip_runtime.h>
#include <cmath>

#define NBLK 3456   // 2 * 12 * 12 * 12 blocks of 16^3

#define DPP_SHR1 0x111   // y-1 neighbor source (row_shr:1)
#define DPP_SHL1 0x101   // y+1 neighbor source (row_shl:1)

// old = v, bound_ctrl = 0: row-edge lanes keep v  -> op(v,v)=v = pad identity
// for min/max/and/or.  Fusable to single v_op_dpp.
template<int CTRL>
__device__ __forceinline__ float dpp_keep_f(float v) {
  return __int_as_float(__builtin_amdgcn_update_dpp(
      __float_as_int(v), __float_as_int(v), CTRL, 0xF, 0xF, false));
}
// bound_ctrl = 1: row-edge lanes get 0 -> exact 0-pad for sums.
template<int CTRL>
__device__ __forceinline__ float dpp_zero_f(float v) {
  return __int_as_float(__builtin_amdgcn_update_dpp(
      0, __float_as_int(v), CTRL, 0xF, 0xF, true));
}
template<int CTRL>
__device__ __forceinline__ unsigned dpp_keep_u(unsigned v) {
  return (unsigned)__builtin_amdgcn_update_dpp((int)v, (int)v, CTRL, 0xF, 0xF, false);
}
template<int CTRL>
__device__ __forceinline__ unsigned dpp_zero_u(unsigned v) {
  return (unsigned)__builtin_amdgcn_update_dpp(0, (int)v, CTRL, 0xF, 0xF, true);
}

// LDS column layout: float4 chunk c (z=4c..4c+3) of column (x,y) at
// index (c*18 + x+1)*16 + y.  x pad slots at x=-1 -> 0 and x=16 -> 17.
#define COL_IDX(c, xx) (((c)*18 + (xx) + 1)*16 + y)

// NOTE: no min-waves arg. (256,8) capped VGPR at 32 -> full spill of the
// register columns (WRITE_SIZE 0.1 MB -> 906 MB, 6x slowdown). Body fits in
// ~60 VGPR which already permits 8 waves/SIMD; occupancy is LDS-limited.
__global__ __launch_bounds__(256)
void fused_blocks(const float* __restrict__ pred, const float* __restrict__ gtp,
                  const float* __restrict__ w1p, const float* __restrict__ w2p,
                  float* __restrict__ acc,   // 5 f32 sums + u32 ticket (zeroed)
                  float* __restrict__ out)
{
  __shared__ float4 buf[1152];                    // 18432 B, multi-purpose
  unsigned* m_ex = (unsigned*)buf;                // 288 u32 (bytes 0..1151)
  float*    red  = ((float*)buf) + 512;           // 36 f32  (bytes 2048..2191)

  const int tid = threadIdx.x;
  const int x = tid >> 4;
  const int y = tid & 15;

  const int b  = blockIdx.x;
  const int n  = b / 1728;
  const int r  = b - n * 1728;
  const int bz = r / 144;
  const int r2 = r - bz * 144;
  const int bx = r2 / 12;
  const int by = r2 - bx * 12;

  const size_t base = (size_t)(n * 192 + bz * 16) * 36864
                    + (size_t)(bx * 16 + x) * 192 + (size_t)(by * 16 + y);

  const float INF = __builtin_inff();

  auto write_pads = [&](float pv) {
    if (tid < 128) {
      const int c  = tid >> 5;
      const int xi = ((tid >> 4) & 1) ? 17 : 0;
      const int yy = tid & 15;
      buf[(c * 18 + xi) * 16 + yy] = make_float4(pv, pv, pv, pv);
    }
  };

  // ---- loads: p column + g column (g consumed immediately) ----
  float p[16];
  #pragma unroll
  for (int z = 0; z < 16; ++z) p[z] = pred[base + (size_t)z * 36864];

  unsigned gm = 0u;
  float sp2 = 0.f, spg = 0.f;
  #pragma unroll
  for (int z = 0; z < 16; ++z) {
    float gz = gtp[base + (size_t)z * 36864];
    sp2 = fmaf(p[z], p[z], sp2);
    spg = fmaf(p[z], gz, spg);
    if (gz > 0.5f) gm |= (1u << z);
  }

  // ---------------- pred boundary (3^3 laplacian, zero pad) ----------------
  float szy[16];
  {
    float sy[16];
    #pragma unroll
    for (int z = 0; z < 16; ++z) {
      float v = p[z];
      sy[z] = v + dpp_zero_f<DPP_SHR1>(v) + dpp_zero_f<DPP_SHL1>(v);
    }
    #pragma unroll
    for (int z = 0; z < 16; ++z) {
      float s = sy[z];
      if (z > 0)  s += sy[z-1];
      if (z < 15) s += sy[z+1];
      szy[z] = s;
    }
  }
  #pragma unroll
  for (int c = 0; c < 4; ++c)
    buf[COL_IDX(c, x)] = make_float4(szy[4*c], szy[4*c+1], szy[4*c+2], szy[4*c+3]);
  write_pads(0.f);
  __syncthreads();                                             // L1

  unsigned pm_bdr = 0u;
  #pragma unroll
  for (int c = 0; c < 4; ++c) {
    float4 a4 = buf[COL_IDX(c, x - 1)];
    float4 b4 = buf[COL_IDX(c, x + 1)];
    float sm[4] = {a4.x + b4.x, a4.y + b4.y, a4.z + b4.z, a4.w + b4.w};
    #pragma unroll
    for (int j = 0; j < 4; ++j) {
      const int z = 4*c + j;
      float bb = fmaf(27.f, p[z], -(szy[z] + sm[j]));
      if (bb > 0.1f) pm_bdr |= (1u << z);
    }
  }
  __syncthreads();                                             // L2

  // ---------------- pred soft skeleton (4x erode+dilate) ----------------
  #pragma unroll
  for (int c = 0; c < 4; ++c)
    buf[COL_IDX(c, x)] = make_float4(p[4*c], p[4*c+1], p[4*c+2], p[4*c+3]);
  write_pads(INF);
  __syncthreads();                                             // B0

  float cur[16], skl[16];
  #pragma unroll
  for (int z = 0; z < 16; ++z) { cur[z] = p[z]; skl[z] = 0.f; }

  for (int k = 0; k < 4; ++k) {
    float xm[16], xp[16];
    #pragma unroll
    for (int c = 0; c < 4; ++c) {
      float4 a4 = buf[COL_IDX(c, x - 1)];
      float4 b4 = buf[COL_IDX(c, x + 1)];
      xm[4*c] = a4.x; xm[4*c+1] = a4.y; xm[4*c+2] = a4.z; xm[4*c+3] = a4.w;
      xp[4*c] = b4.x; xp[4*c+1] = b4.y; xp[4*c+2] = b4.z; xp[4*c+3] = b4.w;
    }
    // erode: min over 7-point cross (+INF pads are in LDS / DPP identity)
    float en[16];
    #pragma unroll
    for (int z = 0; z < 16; ++z) {
      float v = cur[z];
      float m = fminf(v, fminf(dpp_keep_f<DPP_SHR1>(v), dpp_keep_f<DPP_SHL1>(v)));
      if (z > 0)  m = fminf(m, cur[z-1]);
      if (z < 15) m = fminf(m, cur[z+1]);
      en[z] = fminf(m, fminf(xm[z], xp[z]));
    }
    // dilate(en) in y,z (in-register)
    float ty[16], tz[16];
    #pragma unroll
    for (int z = 0; z < 16; ++z) {
      float v = en[z];
      ty[z] = fmaxf(v, fmaxf(dpp_keep_f<DPP_SHR1>(v), dpp_keep_f<DPP_SHL1>(v)));
    }
    #pragma unroll
    for (int z = 0; z < 16; ++z) {
      float m = ty[z];
      if (z > 0)  m = fmaxf(m, ty[z-1]);
      if (z < 15) m = fmaxf(m, ty[z+1]);
      tz[z] = m;
    }
    __syncthreads();                                           // B1: cur reads done
    #pragma unroll
    for (int c = 0; c < 4; ++c)
      buf[COL_IDX(c, x)] = make_float4(tz[4*c], tz[4*c+1], tz[4*c+2], tz[4*c+3]);
    write_pads(-INF);
    __syncthreads();                                           // B2: tz visible
    #pragma unroll
    for (int c = 0; c < 4; ++c) {
      float4 a4 = buf[COL_IDX(c, x - 1)];
      float4 b4 = buf[COL_IDX(c, x + 1)];
      float dm[4] = {fmaxf(a4.x, b4.x), fmaxf(a4.y, b4.y),
                     fmaxf(a4.z, b4.z), fmaxf(a4.w, b4.w)};
      #pragma unroll
      for (int j = 0; j < 4; ++j) {
        const int z = 4*c + j;
        float D = fmaxf(tz[z], dm[j]);
        float delta = fmaxf(cur[z] - D, 0.f);
        skl[z] += fmaxf(fmaf(-skl[z], delta, delta), 0.f);
        cur[z] = en[z];
      }
    }
    if (k < 3) {
      __syncthreads();                                         // B3: tz reads done
      #pragma unroll
      for (int c = 0; c < 4; ++c)
        buf[COL_IDX(c, x)] = make_float4(en[4*c], en[4*c+1], en[4*c+2], en[4*c+3]);
      write_pads(INF);
      __syncthreads();                                         // B4: en visible
    }
  }
  __syncthreads();   // float-buf reads done before m_ex overlay

  // ---------------- gt phase: exact bit-domain morphology ----------------
  // gt boundary: bdr = g & ~AND27(g) with zero padding
  unsigned ly  = gm & dpp_zero_u<DPP_SHR1>(gm) & dpp_zero_u<DPP_SHL1>(gm);
  unsigned lzy = ly & (ly >> 1) & ((ly << 1) & 0xFFFFu);
  m_ex[(x + 1) * 16 + y] = lzy;
  if (tid < 32) m_ex[((tid >> 4) ? 17 : 0) * 16 + (tid & 15)] = 0u;
  __syncthreads();                                             // G1
  unsigned gm_bdr = gm & ~(m_ex[x * 16 + y] & lzy & m_ex[(x + 2) * 16 + y]);

  // gt soft skeleton in bits (erode=AND w/ 1-pad, dilate=OR w/ 0-pad)
  unsigned curm = gm, sklm = 0u;
  for (int k = 0; k < 4; ++k) {
    __syncthreads();                                           // G2
    m_ex[(x + 1) * 16 + y] = curm;
    if (tid < 32) m_ex[((tid >> 4) ? 17 : 0) * 16 + (tid & 15)] = 0xFFFFu;
    __syncthreads();                                           // G3
    unsigned em = curm
        & dpp_keep_u<DPP_SHR1>(curm) & dpp_keep_u<DPP_SHL1>(curm)
        & ((curm >> 1) | 0x8000u) & ((curm << 1) | 1u)
        & m_ex[x * 16 + y] & m_ex[(x + 2) * 16 + y];
    em &= 0xFFFFu;
    unsigned dy  = em | dpp_keep_u<DPP_SHR1>(em) | dpp_keep_u<DPP_SHL1>(em);
    unsigned dzy = (dy | (dy >> 1) | (dy << 1)) & 0xFFFFu;
    __syncthreads();                                           // G4
    m_ex[(x + 1) * 16 + y] = dzy;
    if (tid < 32) m_ex[((tid >> 4) ? 17 : 0) * 16 + (tid & 15)] = 0u;
    __syncthreads();                                           // G5
    unsigned D = m_ex[x * 16 + y] | dzy | m_ex[(x + 2) * 16 + y];
    sklm |= curm & ~D;
    curm = em;
  }

  // ---------------- per-block reductions ----------------
  float vals[9];
  {
    float tcl = 0.f, scl = 0.f;
    #pragma unroll
    for (int z = 0; z < 16; ++z) {
      scl += skl[z];
      tcl += ((sklm >> z) & 1u) ? skl[z] : 0.f;
    }
    vals[0] = tcl;                                   // sum g_cl * p_cl
    vals[1] = scl;                                   // sum p_cl
    vals[2] = (float)__popc(sklm);                   // sum g_cl
    vals[3] = (float)__popc(pm_bdr & gm_bdr);        // bdr tp
    vals[4] = (float)__popc(pm_bdr);                 // sum p_bdr
    vals[5] = (float)__popc(gm_bdr);                 // sum g_bdr
    vals[6] = spg;                                   // dice: sum p*g
    vals[7] = sp2;                                   // dice: sum p*p
    vals[8] = (float)__popc(gm);                     // dice: sum g*g
  }
  #pragma unroll
  for (int j = 0; j < 9; ++j) {
    float v = vals[j];
    #pragma unroll
    for (int off = 32; off; off >>= 1) v += __shfl_xor(v, off);
    vals[j] = v;
  }
  if ((tid & 63) == 0) {
    #pragma unroll
    for (int j = 0; j < 9; ++j) red[(tid >> 6) * 9 + j] = vals[j];
  }
  __syncthreads();                                             // R1
  if (tid == 0) {
    float t[9];
    #pragma unroll
    for (int j = 0; j < 9; ++j) t[j] = red[j] + red[9 + j] + red[18 + j] + red[27 + j];
    const float s = 1e-8f;
    // boundary tversky
    float tp = t[3], fp = t[4] - t[3], fn = t[5] - t[3];
    float den = fp + fn + s;
    float alpha = 0.5f + 0.5f * ((fp + s) / den);
    float beta  = 0.5f + 0.5f * ((fn + s) / den);
    float lb = 1.f - (tp + s) / (tp + alpha * fp + beta * fn + s);
    // centerline tversky
    float tpc = t[0], fpc = t[1] - t[0], fnc = t[2] - t[0];
    float denc = fpc + fnc + s;
    float alphac = 0.5f + 0.5f * ((fpc + s) / denc);
    float betac  = 0.5f + 0.5f * ((fnc + s) / denc);
    float lc = 1.f - (tpc + s) / (tpc + alphac * fpc + betac * fnc + s);

    atomicAdd(&acc[0], lb);
    atomicAdd(&acc[1], lc);
    atomicAdd(&acc[2], t[6]);
    atomicAdd(&acc[3], t[7]);
    atomicAdd(&acc[4], t[8]);
    __threadfence();
    unsigned* cnt = (unsigned*)(acc + 5);
    unsigned ticket = atomicAdd(cnt, 1u);
    if (ticket == NBLK - 1) {                 // last block: finalize
      double t0 = (double)atomicAdd(&acc[0], 0.f);
      double t1 = (double)atomicAdd(&acc[1], 0.f);
      double t2 = (double)atomicAdd(&acc[2], 0.f);
      double t3 = (double)atomicAdd(&acc[3], 0.f);
      double t4 = (double)atomicAdd(&acc[4], 0.f);
      double denom = t3 + t4;
      if (denom < 1e-6) denom = 1e-6;
      double dice = 2.0 * t2 / denom;
      double dl = 1.0 - dice;
      double w1 = (double)w1p[0], w2 = (double)w2p[0];
      double edge = (t0 / (w1 * w1) + t1 / (w2 * w2)) / (2.0 * (double)NBLK)
                  + log(1.0 + fabs(w1) * fabs(w2));
      out[0] = (float)((dice < 0.8) ? dl : (dl + edge));
    }
  }
}

extern "C" void kernel_launch(void* const* d_in, const int* in_sizes, int n_in,
                              void* d_out, int out_size, void* d_ws, size_t ws_size,
                              hipStream_t stream)
{
  const float* pred = (const float*)d_in[0];
  const float* gtp  = (const float*)d_in[1];
  const float* w1   = (const float*)d_in[2];
  const float* w2   = (const float*)d_in[3];

  hipMemsetAsync(d_ws, 0, 32, stream);   // 5 f32 accumulators + ticket counter
  fused_blocks<<<NBLK, 256, 0, stream>>>(pred, gtp, w1, w2,
                                         (float*)d_ws, (float*)d_out);
}

// Round 5
// 180.978 us; speedup vs baseline: 3.6776x; 2.1375x over previous
//
#include <hip/hip_runtime.h>
#include <cmath>

#define NBLK 3456   // 2 * 12 * 12 * 12 blocks of 16^3

#define DPP_SHR1 0x111   // y-1 neighbor source (row_shr:1)
#define DPP_SHL1 0x101   // y+1 neighbor source (row_shl:1)

// old = v, bound_ctrl = 0: row-edge lanes keep v  -> op(v,v)=v = pad identity
// for min/max/and/or.  Fusable to single v_op_dpp.
template<int CTRL>
__device__ __forceinline__ float dpp_keep_f(float v) {
  return __int_as_float(__builtin_amdgcn_update_dpp(
      __float_as_int(v), __float_as_int(v), CTRL, 0xF, 0xF, false));
}
// bound_ctrl = 1: row-edge lanes get 0 -> exact 0-pad for sums.
template<int CTRL>
__device__ __forceinline__ float dpp_zero_f(float v) {
  return __int_as_float(__builtin_amdgcn_update_dpp(
      0, __float_as_int(v), CTRL, 0xF, 0xF, true));
}
template<int CTRL>
__device__ __forceinline__ unsigned dpp_keep_u(unsigned v) {
  return (unsigned)__builtin_amdgcn_update_dpp((int)v, (int)v, CTRL, 0xF, 0xF, false);
}
template<int CTRL>
__device__ __forceinline__ unsigned dpp_zero_u(unsigned v) {
  return (unsigned)__builtin_amdgcn_update_dpp(0, (int)v, CTRL, 0xF, 0xF, true);
}

// LDS column layout: float4 chunk c (z=4c..4c+3) of column (x,y) at
// index (c*18 + x+1)*16 + y.  x pad slots at x=-1 -> 0 and x=16 -> 17.
#define COL_IDX(c, xx) (((c)*18 + (xx) + 1)*16 + y)

// No min-waves arg: (256,8) forced VGPR<=32 -> full spill (R3, 6x slower).
// No atomic/fence tail: 21k same-line device atomics + 3456 threadfences
// serialized ~240us (R4, 3x slower). Per-block stores + tiny finalize kernel.
__global__ __launch_bounds__(256)
void fused_blocks(const float* __restrict__ pred, const float* __restrict__ gtp,
                  float* __restrict__ ws)
{
  __shared__ float4 buf[1152];                    // 18432 B, multi-purpose
  unsigned* m_ex = (unsigned*)buf;                // 288 u32 (bytes 0..1151)
  float*    red  = ((float*)buf) + 512;           // 36 f32  (bytes 2048..2191)

  const int tid = threadIdx.x;
  const int x = tid >> 4;
  const int y = tid & 15;

  const int b  = blockIdx.x;
  const int n  = b / 1728;
  const int r  = b - n * 1728;
  const int bz = r / 144;
  const int r2 = r - bz * 144;
  const int bx = r2 / 12;
  const int by = r2 - bx * 12;

  const size_t base = (size_t)(n * 192 + bz * 16) * 36864
                    + (size_t)(bx * 16 + x) * 192 + (size_t)(by * 16 + y);

  const float INF = __builtin_inff();

  auto write_pads = [&](float pv) {
    if (tid < 128) {
      const int c  = tid >> 5;
      const int xi = ((tid >> 4) & 1) ? 17 : 0;
      const int yy = tid & 15;
      buf[(c * 18 + xi) * 16 + yy] = make_float4(pv, pv, pv, pv);
    }
  };

  // ---- loads: p column + g column (g consumed immediately) ----
  float p[16];
  #pragma unroll
  for (int z = 0; z < 16; ++z) p[z] = pred[base + (size_t)z * 36864];

  unsigned gm = 0u;
  float sp2 = 0.f, spg = 0.f;
  #pragma unroll
  for (int z = 0; z < 16; ++z) {
    float gz = gtp[base + (size_t)z * 36864];
    sp2 = fmaf(p[z], p[z], sp2);
    spg = fmaf(p[z], gz, spg);
    if (gz > 0.5f) gm |= (1u << z);
  }

  // ---------------- pred boundary (3^3 laplacian, zero pad) ----------------
  float szy[16];
  {
    float sy[16];
    #pragma unroll
    for (int z = 0; z < 16; ++z) {
      float v = p[z];
      sy[z] = v + dpp_zero_f<DPP_SHR1>(v) + dpp_zero_f<DPP_SHL1>(v);
    }
    #pragma unroll
    for (int z = 0; z < 16; ++z) {
      float s = sy[z];
      if (z > 0)  s += sy[z-1];
      if (z < 15) s += sy[z+1];
      szy[z] = s;
    }
  }
  #pragma unroll
  for (int c = 0; c < 4; ++c)
    buf[COL_IDX(c, x)] = make_float4(szy[4*c], szy[4*c+1], szy[4*c+2], szy[4*c+3]);
  write_pads(0.f);
  __syncthreads();                                             // L1

  unsigned pm_bdr = 0u;
  #pragma unroll
  for (int c = 0; c < 4; ++c) {
    float4 a4 = buf[COL_IDX(c, x - 1)];
    float4 b4 = buf[COL_IDX(c, x + 1)];
    float sm[4] = {a4.x + b4.x, a4.y + b4.y, a4.z + b4.z, a4.w + b4.w};
    #pragma unroll
    for (int j = 0; j < 4; ++j) {
      const int z = 4*c + j;
      float bb = fmaf(27.f, p[z], -(szy[z] + sm[j]));
      if (bb > 0.1f) pm_bdr |= (1u << z);
    }
  }
  __syncthreads();                                             // L2

  // ---------------- pred soft skeleton (4x erode+dilate) ----------------
  #pragma unroll
  for (int c = 0; c < 4; ++c)
    buf[COL_IDX(c, x)] = make_float4(p[4*c], p[4*c+1], p[4*c+2], p[4*c+3]);
  write_pads(INF);
  __syncthreads();                                             // B0

  float cur[16], skl[16];
  #pragma unroll
  for (int z = 0; z < 16; ++z) { cur[z] = p[z]; skl[z] = 0.f; }

  for (int k = 0; k < 4; ++k) {
    float xm[16], xp[16];
    #pragma unroll
    for (int c = 0; c < 4; ++c) {
      float4 a4 = buf[COL_IDX(c, x - 1)];
      float4 b4 = buf[COL_IDX(c, x + 1)];
      xm[4*c] = a4.x; xm[4*c+1] = a4.y; xm[4*c+2] = a4.z; xm[4*c+3] = a4.w;
      xp[4*c] = b4.x; xp[4*c+1] = b4.y; xp[4*c+2] = b4.z; xp[4*c+3] = b4.w;
    }
    // erode: min over 7-point cross (+INF pads are in LDS / DPP identity)
    float en[16];
    #pragma unroll
    for (int z = 0; z < 16; ++z) {
      float v = cur[z];
      float m = fminf(v, fminf(dpp_keep_f<DPP_SHR1>(v), dpp_keep_f<DPP_SHL1>(v)));
      if (z > 0)  m = fminf(m, cur[z-1]);
      if (z < 15) m = fminf(m, cur[z+1]);
      en[z] = fminf(m, fminf(xm[z], xp[z]));
    }
    // dilate(en) in y,z (in-register)
    float ty[16], tz[16];
    #pragma unroll
    for (int z = 0; z < 16; ++z) {
      float v = en[z];
      ty[z] = fmaxf(v, fmaxf(dpp_keep_f<DPP_SHR1>(v), dpp_keep_f<DPP_SHL1>(v)));
    }
    #pragma unroll
    for (int z = 0; z < 16; ++z) {
      float m = ty[z];
      if (z > 0)  m = fmaxf(m, ty[z-1]);
      if (z < 15) m = fmaxf(m, ty[z+1]);
      tz[z] = m;
    }
    __syncthreads();                                           // B1: cur reads done
    #pragma unroll
    for (int c = 0; c < 4; ++c)
      buf[COL_IDX(c, x)] = make_float4(tz[4*c], tz[4*c+1], tz[4*c+2], tz[4*c+3]);
    write_pads(-INF);
    __syncthreads();                                           // B2: tz visible
    #pragma unroll
    for (int c = 0; c < 4; ++c) {
      float4 a4 = buf[COL_IDX(c, x - 1)];
      float4 b4 = buf[COL_IDX(c, x + 1)];
      float dm[4] = {fmaxf(a4.x, b4.x), fmaxf(a4.y, b4.y),
                     fmaxf(a4.z, b4.z), fmaxf(a4.w, b4.w)};
      #pragma unroll
      for (int j = 0; j < 4; ++j) {
        const int z = 4*c + j;
        float D = fmaxf(tz[z], dm[j]);
        float delta = fmaxf(cur[z] - D, 0.f);
        skl[z] += fmaxf(fmaf(-skl[z], delta, delta), 0.f);
        cur[z] = en[z];
      }
    }
    if (k < 3) {
      __syncthreads();                                         // B3: tz reads done
      #pragma unroll
      for (int c = 0; c < 4; ++c)
        buf[COL_IDX(c, x)] = make_float4(en[4*c], en[4*c+1], en[4*c+2], en[4*c+3]);
      write_pads(INF);
      __syncthreads();                                         // B4: en visible
    }
  }
  __syncthreads();   // float-buf reads done before m_ex overlay

  // ---------------- gt phase: exact bit-domain morphology ----------------
  // gt boundary: bdr = g & ~AND27(g) with zero padding
  unsigned ly  = gm & dpp_zero_u<DPP_SHR1>(gm) & dpp_zero_u<DPP_SHL1>(gm);
  unsigned lzy = ly & (ly >> 1) & ((ly << 1) & 0xFFFFu);
  m_ex[(x + 1) * 16 + y] = lzy;
  if (tid < 32) m_ex[((tid >> 4) ? 17 : 0) * 16 + (tid & 15)] = 0u;
  __syncthreads();                                             // G1
  unsigned gm_bdr = gm & ~(m_ex[x * 16 + y] & lzy & m_ex[(x + 2) * 16 + y]);

  // gt soft skeleton in bits (erode=AND w/ 1-pad, dilate=OR w/ 0-pad)
  unsigned curm = gm, sklm = 0u;
  for (int k = 0; k < 4; ++k) {
    __syncthreads();                                           // G2
    m_ex[(x + 1) * 16 + y] = curm;
    if (tid < 32) m_ex[((tid >> 4) ? 17 : 0) * 16 + (tid & 15)] = 0xFFFFu;
    __syncthreads();                                           // G3
    unsigned em = curm
        & dpp_keep_u<DPP_SHR1>(curm) & dpp_keep_u<DPP_SHL1>(curm)
        & ((curm >> 1) | 0x8000u) & ((curm << 1) | 1u)
        & m_ex[x * 16 + y] & m_ex[(x + 2) * 16 + y];
    em &= 0xFFFFu;
    unsigned dy  = em | dpp_keep_u<DPP_SHR1>(em) | dpp_keep_u<DPP_SHL1>(em);
    unsigned dzy = (dy | (dy >> 1) | (dy << 1)) & 0xFFFFu;
    __syncthreads();                                           // G4
    m_ex[(x + 1) * 16 + y] = dzy;
    if (tid < 32) m_ex[((tid >> 4) ? 17 : 0) * 16 + (tid & 15)] = 0u;
    __syncthreads();                                           // G5
    unsigned D = m_ex[x * 16 + y] | dzy | m_ex[(x + 2) * 16 + y];
    sklm |= curm & ~D;
    curm = em;
  }

  // ---------------- per-block reductions ----------------
  float vals[9];
  {
    float tcl = 0.f, scl = 0.f;
    #pragma unroll
    for (int z = 0; z < 16; ++z) {
      scl += skl[z];
      tcl += ((sklm >> z) & 1u) ? skl[z] : 0.f;
    }
    vals[0] = tcl;                                   // sum g_cl * p_cl
    vals[1] = scl;                                   // sum p_cl
    vals[2] = (float)__popc(sklm);                   // sum g_cl
    vals[3] = (float)__popc(pm_bdr & gm_bdr);        // bdr tp
    vals[4] = (float)__popc(pm_bdr);                 // sum p_bdr
    vals[5] = (float)__popc(gm_bdr);                 // sum g_bdr
    vals[6] = spg;                                   // dice: sum p*g
    vals[7] = sp2;                                   // dice: sum p*p
    vals[8] = (float)__popc(gm);                     // dice: sum g*g
  }
  #pragma unroll
  for (int j = 0; j < 9; ++j) {
    float v = vals[j];
    #pragma unroll
    for (int off = 32; off; off >>= 1) v += __shfl_xor(v, off);
    vals[j] = v;
  }
  if ((tid & 63) == 0) {
    #pragma unroll
    for (int j = 0; j < 9; ++j) red[(tid >> 6) * 9 + j] = vals[j];
  }
  __syncthreads();                                             // R1
  if (tid == 0) {
    float t[9];
    #pragma unroll
    for (int j = 0; j < 9; ++j) t[j] = red[j] + red[9 + j] + red[18 + j] + red[27 + j];
    const float s = 1e-8f;
    // boundary tversky
    float tp = t[3], fp = t[4] - t[3], fn = t[5] - t[3];
    float den = fp + fn + s;
    float alpha = 0.5f + 0.5f * ((fp + s) / den);
    float beta  = 0.5f + 0.5f * ((fn + s) / den);
    float lb = 1.f - (tp + s) / (tp + alpha * fp + beta * fn + s);
    // centerline tversky
    float tpc = t[0], fpc = t[1] - t[0], fnc = t[2] - t[0];
    float denc = fpc + fnc + s;
    float alphac = 0.5f + 0.5f * ((fpc + s) / denc);
    float betac  = 0.5f + 0.5f * ((fnc + s) / denc);
    float lc = 1.f - (tpc + s) / (tpc + alphac * fpc + betac * fnc + s);
    float* o = ws + (size_t)b * 8;
    o[0] = lb; o[1] = lc; o[2] = t[6]; o[3] = t[7]; o[4] = t[8];
  }
}

__global__ __launch_bounds__(256)
void finalize_kernel(const float* __restrict__ ws, const float* __restrict__ w1p,
                     const float* __restrict__ w2p, float* __restrict__ out)
{
  __shared__ double red2[20];
  double a[5] = {0.0, 0.0, 0.0, 0.0, 0.0};
  for (int i = threadIdx.x; i < NBLK; i += 256) {
    const float* o = ws + (size_t)i * 8;
    a[0] += (double)o[0];
    a[1] += (double)o[1];
    a[2] += (double)o[2];
    a[3] += (double)o[3];
    a[4] += (double)o[4];
  }
  #pragma unroll
  for (int j = 0; j < 5; ++j) {
    double v = a[j];
    #pragma unroll
    for (int off = 32; off; off >>= 1) v += __shfl_xor(v, off);
    if ((threadIdx.x & 63) == 0) red2[(threadIdx.x >> 6) * 5 + j] = v;
  }
  __syncthreads();
  if (threadIdx.x == 0) {
    double t[5];
    #pragma unroll
    for (int j = 0; j < 5; ++j) t[j] = red2[j] + red2[5 + j] + red2[10 + j] + red2[15 + j];
    double denom = t[3] + t[4];
    if (denom < 1e-6) denom = 1e-6;
    double dice = 2.0 * t[2] / denom;
    double dl = 1.0 - dice;
    double w1 = (double)w1p[0], w2 = (double)w2p[0];
    double edge = (t[0] / (w1 * w1) + t[1] / (w2 * w2)) / (2.0 * (double)NBLK)
                + log(1.0 + fabs(w1) * fabs(w2));
    out[0] = (float)((dice < 0.8) ? dl : (dl + edge));
  }
}

extern "C" void kernel_launch(void* const* d_in, const int* in_sizes, int n_in,
                              void* d_out, int out_size, void* d_ws, size_t ws_size,
                              hipStream_t stream)
{
  const float* pred = (const float*)d_in[0];
  const float* gtp  = (const float*)d_in[1];
  const float* w1   = (const float*)d_in[2];
  const float* w2   = (const float*)d_in[3];
  float* ws = (float*)d_ws;   // NBLK * 8 floats = 110,592 B

  fused_blocks<<<NBLK, 256, 0, stream>>>(pred, gtp, ws);
  finalize_kernel<<<1, 256, 0, stream>>>(ws, w1, w2, (float*)d_out);
}

// Round 6
// 179.650 us; speedup vs baseline: 3.7048x; 1.0074x over previous
//
#include <hip/hip_runtime.h>
#include <cmath>

#define NBLK 3456   // 2 * 12 * 12 * 12 blocks of 16^3

#define DPP_SHR1 0x111   // y-1 neighbor source (row_shr:1)
#define DPP_SHL1 0x101   // y+1 neighbor source (row_shl:1)

// old = v, bound_ctrl = 0: row-edge lanes keep v  -> op(v,v)=v = pad identity
// for min/max/and/or.  Fusable to single v_op_dpp.
template<int CTRL>
__device__ __forceinline__ float dpp_keep_f(float v) {
  return __int_as_float(__builtin_amdgcn_update_dpp(
      __float_as_int(v), __float_as_int(v), CTRL, 0xF, 0xF, false));
}
// bound_ctrl = 1: row-edge lanes get 0 -> exact 0-pad for sums.
template<int CTRL>
__device__ __forceinline__ float dpp_zero_f(float v) {
  return __int_as_float(__builtin_amdgcn_update_dpp(
      0, __float_as_int(v), CTRL, 0xF, 0xF, true));
}
template<int CTRL>
__device__ __forceinline__ unsigned dpp_keep_u(unsigned v) {
  return (unsigned)__builtin_amdgcn_update_dpp((int)v, (int)v, CTRL, 0xF, 0xF, false);
}
template<int CTRL>
__device__ __forceinline__ unsigned dpp_zero_u(unsigned v) {
  return (unsigned)__builtin_amdgcn_update_dpp(0, (int)v, CTRL, 0xF, 0xF, true);
}

// LDS column layout: float4 chunk c (z=4c..4c+3) of column (x,y) at
// index (c*18 + x+1)*16 + y.  x pad slots at x=-1 -> 0 and x=16 -> 17.
#define COL_IDX(c, xx) (((c)*18 + (xx) + 1)*16 + y)

// No min-waves arg: (256,8) forced VGPR<=32 -> full spill (R3, 6x slower).
// No atomic tail: 21k same-line device atomics serialized ~240us (R4).
// This revision is a register diet targeting the 64-VGPR occupancy cliff
// (m69: waves/SIMD halve at 64): no xm/xp/ty/tz arrays, LDS-stashed sp2/spg.
__global__ __launch_bounds__(256)
void fused_blocks(const float* __restrict__ pred, const float* __restrict__ gtp,
                  float* __restrict__ ws)
{
  __shared__ float4 buf[1152];                    // 18432 B, multi-purpose
  __shared__ float  stash[512];                   // 2048 B: sp2, spg parked
  unsigned* m_ex = (unsigned*)buf;                // 288 u32 (bytes 0..1151)
  float*    red  = ((float*)buf) + 512;           // 36 f32  (bytes 2048..2191)

  const int tid = threadIdx.x;
  const int x = tid >> 4;
  const int y = tid & 15;

  const int b  = blockIdx.x;
  const int n  = b / 1728;
  const int r  = b - n * 1728;
  const int bz = r / 144;
  const int r2 = r - bz * 144;
  const int bx = r2 / 12;
  const int by = r2 - bx * 12;

  const size_t base = (size_t)(n * 192 + bz * 16) * 36864
                    + (size_t)(bx * 16 + x) * 192 + (size_t)(by * 16 + y);

  const float INF = __builtin_inff();

  auto write_pads = [&](float pv) {
    if (tid < 128) {
      const int c  = tid >> 5;
      const int xi = ((tid >> 4) & 1) ? 17 : 0;
      const int yy = tid & 15;
      buf[(c * 18 + xi) * 16 + yy] = make_float4(pv, pv, pv, pv);
    }
  };

  // ---- loads: p column + g column (g consumed immediately) ----
  float p[16];
  #pragma unroll
  for (int z = 0; z < 16; ++z) p[z] = pred[base + (size_t)z * 36864];

  unsigned gm = 0u;
  {
    float sp2 = 0.f, spg = 0.f;
    #pragma unroll
    for (int z = 0; z < 16; ++z) {
      float gz = gtp[base + (size_t)z * 36864];
      sp2 = fmaf(p[z], p[z], sp2);
      spg = fmaf(p[z], gz, spg);
      if (gz > 0.5f) gm |= (1u << z);
    }
    // park in LDS until the epilogue (ends register live ranges; the
    // conservative LDS aliasing forces a reload later, which is what we want)
    stash[tid]       = sp2;
    stash[256 + tid] = spg;
  }

  // ---------------- pred boundary (3^3 laplacian, zero pad) ----------------
  float szy[16];
  {
    // sy(z) = y-convolved p, rolling 3-window for the z convolution
    float sprev = 0.f;
    float v0 = p[0];
    float scur = v0 + dpp_zero_f<DPP_SHR1>(v0) + dpp_zero_f<DPP_SHL1>(v0);
    #pragma unroll
    for (int z = 0; z < 16; ++z) {
      float snext;
      if (z < 15) {
        float v = p[z + 1];
        snext = v + dpp_zero_f<DPP_SHR1>(v) + dpp_zero_f<DPP_SHL1>(v);
      } else snext = 0.f;
      szy[z] = sprev + scur + snext;
      sprev = scur; scur = snext;
    }
  }
  #pragma unroll
  for (int c = 0; c < 4; ++c)
    buf[COL_IDX(c, x)] = make_float4(szy[4*c], szy[4*c+1], szy[4*c+2], szy[4*c+3]);
  write_pads(0.f);
  __syncthreads();                                             // L1

  unsigned pm_bdr = 0u;
  #pragma unroll
  for (int c = 0; c < 4; ++c) {
    float4 a4 = buf[COL_IDX(c, x - 1)];
    float4 b4 = buf[COL_IDX(c, x + 1)];
    #pragma unroll
    for (int j = 0; j < 4; ++j) {
      const int z = 4*c + j;
      float bb = fmaf(27.f, p[z], -(szy[z] + ((&a4.x)[j] + (&b4.x)[j])));
      if (bb > 0.1f) pm_bdr |= (1u << z);
    }
  }
  __syncthreads();                                             // L2

  // ---------------- pred soft skeleton (4x erode+dilate) ----------------
  #pragma unroll
  for (int c = 0; c < 4; ++c)
    buf[COL_IDX(c, x)] = make_float4(p[4*c], p[4*c+1], p[4*c+2], p[4*c+3]);
  write_pads(INF);
  __syncthreads();                                             // B0

  float cur[16], skl[16];   // cur aliases p's registers (cur[z]=p[z])
  #pragma unroll
  for (int z = 0; z < 16; ++z) { cur[z] = p[z]; skl[z] = 0.f; }

  for (int k = 0; k < 4; ++k) {
    // erode: min over 7-point cross; x-neighbors consumed per-chunk
    float en[16];
    #pragma unroll
    for (int c = 0; c < 4; ++c) {
      float4 a4 = buf[COL_IDX(c, x - 1)];
      float4 b4 = buf[COL_IDX(c, x + 1)];
      #pragma unroll
      for (int j = 0; j < 4; ++j) {
        const int z = 4*c + j;
        float v  = cur[z];
        float m1 = fminf(dpp_keep_f<DPP_SHR1>(v), v);     // fused dpp min
        float m2 = fminf(dpp_keep_f<DPP_SHL1>(v), m1);    // fused dpp min
        float zl = (z > 0)  ? cur[z-1] : v;
        float zh = (z < 15) ? cur[z+1] : v;
        en[z] = fminf(fminf(m2, fminf(zl, zh)),
                      fminf((&a4.x)[j], (&b4.x)[j]));
      }
    }
    __syncthreads();                                           // B1: cur reads done
    // dilate(en) in y,z with rolling ty window; write tz chunks to LDS
    {
      float v0 = en[0];
      float tprev = -INF;
      float tcur  = fmaxf(dpp_keep_f<DPP_SHL1>(v0),
                          fmaxf(dpp_keep_f<DPP_SHR1>(v0), v0));
      #pragma unroll
      for (int c = 0; c < 4; ++c) {
        float4 w;
        #pragma unroll
        for (int j = 0; j < 4; ++j) {
          const int z = 4*c + j;
          float tnext;
          if (z < 15) {
            float v = en[z + 1];
            tnext = fmaxf(dpp_keep_f<DPP_SHL1>(v),
                          fmaxf(dpp_keep_f<DPP_SHR1>(v), v));
          } else tnext = -INF;
          (&w.x)[j] = fmaxf(fmaxf(tprev, tcur), tnext);
          tprev = tcur; tcur = tnext;
        }
        buf[COL_IDX(c, x)] = w;
      }
    }
    write_pads(-INF);
    __syncthreads();                                           // B2: tz visible
    // skel update: D = max over x-1,x,x+1 tz columns (own col re-read from LDS)
    #pragma unroll
    for (int c = 0; c < 4; ++c) {
      float4 a4 = buf[COL_IDX(c, x - 1)];
      float4 b4 = buf[COL_IDX(c, x + 1)];
      float4 c4 = buf[COL_IDX(c, x)];
      #pragma unroll
      for (int j = 0; j < 4; ++j) {
        const int z = 4*c + j;
        float D = fmaxf(fmaxf((&a4.x)[j], (&b4.x)[j]), (&c4.x)[j]);
        float delta = fmaxf(cur[z] - D, 0.f);
        skl[z] += fmaxf(fmaf(-skl[z], delta, delta), 0.f);
        cur[z] = en[z];
      }
    }
    if (k < 3) {
      __syncthreads();                                         // B3: tz reads done
      #pragma unroll
      for (int c = 0; c < 4; ++c)
        buf[COL_IDX(c, x)] = make_float4(cur[4*c], cur[4*c+1], cur[4*c+2], cur[4*c+3]);
      write_pads(INF);
      __syncthreads();                                         // B4: new cur visible
    }
  }
  __syncthreads();   // float-buf reads done before m_ex overlay

  // ---------------- gt phase: exact bit-domain morphology ----------------
  // gt boundary: bdr = g & ~AND27(g) with zero padding
  unsigned ly  = gm & dpp_zero_u<DPP_SHR1>(gm) & dpp_zero_u<DPP_SHL1>(gm);
  unsigned lzy = ly & (ly >> 1) & ((ly << 1) & 0xFFFFu);
  m_ex[(x + 1) * 16 + y] = lzy;
  if (tid < 32) m_ex[((tid >> 4) ? 17 : 0) * 16 + (tid & 15)] = 0u;
  __syncthreads();                                             // G1
  unsigned gm_bdr = gm & ~(m_ex[x * 16 + y] & lzy & m_ex[(x + 2) * 16 + y]);

  // gt soft skeleton in bits (erode=AND w/ 1-pad, dilate=OR w/ 0-pad)
  unsigned curm = gm, sklm = 0u;
  for (int k = 0; k < 4; ++k) {
    __syncthreads();                                           // G2
    m_ex[(x + 1) * 16 + y] = curm;
    if (tid < 32) m_ex[((tid >> 4) ? 17 : 0) * 16 + (tid & 15)] = 0xFFFFu;
    __syncthreads();                                           // G3
    unsigned em = curm
        & dpp_keep_u<DPP_SHR1>(curm) & dpp_keep_u<DPP_SHL1>(curm)
        & ((curm >> 1) | 0x8000u) & ((curm << 1) | 1u)
        & m_ex[x * 16 + y] & m_ex[(x + 2) * 16 + y];
    em &= 0xFFFFu;
    unsigned dy  = em | dpp_keep_u<DPP_SHR1>(em) | dpp_keep_u<DPP_SHL1>(em);
    unsigned dzy = (dy | (dy >> 1) | (dy << 1)) & 0xFFFFu;
    __syncthreads();                                           // G4
    m_ex[(x + 1) * 16 + y] = dzy;
    if (tid < 32) m_ex[((tid >> 4) ? 17 : 0) * 16 + (tid & 15)] = 0u;
    __syncthreads();                                           // G5
    unsigned D = m_ex[x * 16 + y] | dzy | m_ex[(x + 2) * 16 + y];
    sklm |= curm & ~D;
    curm = em;
  }

  // ---------------- per-block reductions ----------------
  float vals[9];
  {
    float tcl = 0.f, scl = 0.f;
    #pragma unroll
    for (int z = 0; z < 16; ++z) {
      scl += skl[z];
      tcl += ((sklm >> z) & 1u) ? skl[z] : 0.f;
    }
    vals[0] = tcl;                                   // sum g_cl * p_cl
    vals[1] = scl;                                   // sum p_cl
    vals[2] = (float)__popc(sklm);                   // sum g_cl
    vals[3] = (float)__popc(pm_bdr & gm_bdr);        // bdr tp
    vals[4] = (float)__popc(pm_bdr);                 // sum p_bdr
    vals[5] = (float)__popc(gm_bdr);                 // sum g_bdr
    vals[6] = stash[256 + tid];                      // dice: sum p*g
    vals[7] = stash[tid];                            // dice: sum p*p
    vals[8] = (float)__popc(gm);                     // dice: sum g*g
  }
  #pragma unroll
  for (int j = 0; j < 9; ++j) {
    float v = vals[j];
    #pragma unroll
    for (int off = 32; off; off >>= 1) v += __shfl_xor(v, off);
    vals[j] = v;
  }
  if ((tid & 63) == 0) {
    #pragma unroll
    for (int j = 0; j < 9; ++j) red[(tid >> 6) * 9 + j] = vals[j];
  }
  __syncthreads();                                             // R1
  if (tid == 0) {
    float t[9];
    #pragma unroll
    for (int j = 0; j < 9; ++j) t[j] = red[j] + red[9 + j] + red[18 + j] + red[27 + j];
    const float s = 1e-8f;
    // boundary tversky
    float tp = t[3], fp = t[4] - t[3], fn = t[5] - t[3];
    float den = fp + fn + s;
    float alpha = 0.5f + 0.5f * ((fp + s) / den);
    float beta  = 0.5f + 0.5f * ((fn + s) / den);
    float lb = 1.f - (tp + s) / (tp + alpha * fp + beta * fn + s);
    // centerline tversky
    float tpc = t[0], fpc = t[1] - t[0], fnc = t[2] - t[0];
    float denc = fpc + fnc + s;
    float alphac = 0.5f + 0.5f * ((fpc + s) / denc);
    float betac  = 0.5f + 0.5f * ((fnc + s) / denc);
    float lc = 1.f - (tpc + s) / (tpc + alphac * fpc + betac * fnc + s);
    float* o = ws + (size_t)b * 8;
    o[0] = lb; o[1] = lc; o[2] = t[6]; o[3] = t[7]; o[4] = t[8];
  }
}

__global__ __launch_bounds__(256)
void finalize_kernel(const float* __restrict__ ws, const float* __restrict__ w1p,
                     const float* __restrict__ w2p, float* __restrict__ out)
{
  __shared__ double red2[20];
  double a[5] = {0.0, 0.0, 0.0, 0.0, 0.0};
  for (int i = threadIdx.x; i < NBLK; i += 256) {
    const float* o = ws + (size_t)i * 8;
    a[0] += (double)o[0];
    a[1] += (double)o[1];
    a[2] += (double)o[2];
    a[3] += (double)o[3];
    a[4] += (double)o[4];
  }
  #pragma unroll
  for (int j = 0; j < 5; ++j) {
    double v = a[j];
    #pragma unroll
    for (int off = 32; off; off >>= 1) v += __shfl_xor(v, off);
    if ((threadIdx.x & 63) == 0) red2[(threadIdx.x >> 6) * 5 + j] = v;
  }
  __syncthreads();
  if (threadIdx.x == 0) {
    double t[5];
    #pragma unroll
    for (int j = 0; j < 5; ++j) t[j] = red2[j] + red2[5 + j] + red2[10 + j] + red2[15 + j];
    double denom = t[3] + t[4];
    if (denom < 1e-6) denom = 1e-6;
    double dice = 2.0 * t[2] / denom;
    double dl = 1.0 - dice;
    double w1 = (double)w1p[0], w2 = (double)w2p[0];
    double edge = (t[0] / (w1 * w1) + t[1] / (w2 * w2)) / (2.0 * (double)NBLK)
                + log(1.0 + fabs(w1) * fabs(w2));
    out[0] = (float)((dice < 0.8) ? dl : (dl + edge));
  }
}

extern "C" void kernel_launch(void* const* d_in, const int* in_sizes, int n_in,
                              void* d_out, int out_size, void* d_ws, size_t ws_size,
                              hipStream_t stream)
{
  const float* pred = (const float*)d_in[0];
  const float* gtp  = (const float*)d_in[1];
  const float* w1   = (const float*)d_in[2];
  const float* w2   = (const float*)d_in[3];
  float* ws = (float*)d_ws;   // NBLK * 8 floats = 110,592 B

  fused_blocks<<<NBLK, 256, 0, stream>>>(pred, gtp, ws);
  finalize_kernel<<<1, 256, 0, stream>>>(ws, w1, w2, (float*)d_out);
}